// Round 1
// baseline (3859.239 us; speedup 1.0000x reference)
//
#include <hip/hip_runtime.h>
#include <math.h>

#define B_    32
#define H_    28
#define W_    28
#define C_    768
#define D_    64
#define EMB_  64
#define HW_   (H_ * W_)
#define NPOS  (B_ * HW_)          // 25088
#define CWROWS (D_ * D_ * 9)      // 36864

__device__ __forceinline__ float qgelu(float v) {
    return v / (1.f + __expf(-1.702f * v));
}

// ---------------- Stage 1: meta MLP per pixel ----------------
// pbuf[pos*64 + p] = (relu(x_row . w1) + b1) . w2 + b2   (pre-mean)
__global__ void k_meta(const float* __restrict__ x,
                       const float* __restrict__ w1, const float* __restrict__ b1,
                       const float* __restrict__ w2, const float* __restrict__ b2,
                       float* __restrict__ pbuf)
{
    __shared__ float xs[4][C_];
    __shared__ float hs[4][EMB_];
    const int wave = threadIdx.x >> 6;
    const int lane = threadIdx.x & 63;
    const int pos  = blockIdx.x * 4 + wave;   // NPOS % 4 == 0

    const float* xrow = x + (size_t)pos * C_;
    for (int c = lane; c < C_; c += 64) xs[wave][c] = xrow[c];
    __syncthreads();

    float acc = b1[lane];
    const float* wrow = w1 + (size_t)lane * C_;
    #pragma unroll 8
    for (int c = 0; c < C_; ++c) acc = fmaf(xs[wave][c], wrow[c], acc);
    hs[wave][lane] = fmaxf(acc, 0.f);
    __syncthreads();

    float p = b2[lane];
    const float* w2row = w2 + (size_t)lane * EMB_;
    #pragma unroll
    for (int i = 0; i < EMB_; ++i) p = fmaf(hs[wave][i], w2row[i], p);
    pbuf[(size_t)pos * EMB_ + lane] = p;
}

// ---------------- Stage 2: deterministic spatial mean ----------------
__global__ void k_reduce(const float* __restrict__ pbuf, float* __restrict__ prompt)
{
    __shared__ float part[4][EMB_];
    const int b     = blockIdx.x;
    const int lane  = threadIdx.x & 63;
    const int chunk = threadIdx.x >> 6;
    float acc = 0.f;
    for (int i = chunk; i < HW_; i += 4)
        acc += pbuf[((size_t)b * HW_ + i) * EMB_ + lane];
    part[chunk][lane] = acc;
    __syncthreads();
    if (threadIdx.x < EMB_) {
        float s = part[0][threadIdx.x] + part[1][threadIdx.x]
                + part[2][threadIdx.x] + part[3][threadIdx.x];
        prompt[b * EMB_ + threadIdx.x] = s * (1.f / HW_);
    }
}

// ---------------- Stage 3: hypernet -> per-sample conv weights ----------------
// conv_w[b][r] = hyper_b[r] + sum_e (layer_emb[e] + prompt[b][e]) * hyper_w[r][e]
__global__ void k_hyper(const float* __restrict__ prompt, const float* __restrict__ layer_emb,
                        const float* __restrict__ hyper_w, const float* __restrict__ hyper_b,
                        float* __restrict__ conv_w)
{
    __shared__ float fused[B_][EMB_];
    const int tid = threadIdx.x;
    for (int i = tid; i < B_ * EMB_; i += 256) {
        int e = i & (EMB_ - 1);
        fused[i >> 6][e] = layer_emb[e] + prompt[i];
    }
    __syncthreads();

    const int r = blockIdx.x * 256 + tid;     // 36864 rows, grid=144
    float wrow[EMB_];
    const float* hw = hyper_w + (size_t)r * EMB_;
    #pragma unroll
    for (int i = 0; i < EMB_; ++i) wrow[i] = hw[i];
    const float hb = hyper_b[r];

    for (int b = 0; b < B_; ++b) {
        float acc = hb;
        #pragma unroll
        for (int i = 0; i < EMB_; ++i) acc = fmaf(fused[b][i], wrow[i], acc);
        conv_w[(size_t)b * CWROWS + r] = acc;
    }
}

// ---------------- Stage 4: adapter-down + QuickGELU ----------------
__global__ void k_down(const float* __restrict__ x, const float* __restrict__ dw,
                       const float* __restrict__ db, float* __restrict__ xact)
{
    __shared__ float xs[4][C_];
    const int wave = threadIdx.x >> 6;
    const int lane = threadIdx.x & 63;
    const int pos  = blockIdx.x * 4 + wave;

    const float* xrow = x + (size_t)pos * C_;
    for (int c = lane; c < C_; c += 64) xs[wave][c] = xrow[c];
    __syncthreads();

    float acc = db[lane];
    const float* wrow = dw + (size_t)lane * C_;
    #pragma unroll 8
    for (int c = 0; c < C_; ++c) acc = fmaf(xs[wave][c], wrow[c], acc);
    xact[(size_t)pos * D_ + lane] = qgelu(acc);
}

// ---------------- Stage 5: per-sample 3x3 conv + QuickGELU ----------------
// xact layout [B][H][W][D]; cw layout [B][dout][din][3][3]; yact [B][H][W][dout]
__global__ void k_conv(const float* __restrict__ xact, const float* __restrict__ cw,
                       float* __restrict__ yact)
{
    const int idx  = blockIdx.x * 256 + threadIdx.x;   // ((b*H+h)*W+w)*64 + dout
    const int dout = idx & 63;
    const int pos  = idx >> 6;
    const int w    = pos % W_;
    const int t    = pos / W_;
    const int h    = t % H_;
    const int b    = t / H_;

    const float* cwb = cw + (size_t)b * CWROWS + (size_t)dout * (D_ * 9);
    float acc = 0.f;
    #pragma unroll
    for (int kh = 0; kh < 3; ++kh) {
        const int hh = h + kh - 1;
        if (hh < 0 || hh >= H_) continue;
        #pragma unroll
        for (int kw = 0; kw < 3; ++kw) {
            const int ww = w + kw - 1;
            if (ww < 0 || ww >= W_) continue;
            const float* xp = xact + ((size_t)((b * H_ + hh) * W_ + ww)) * D_;
            const float* cp = cwb + (kh * 3 + kw);
            #pragma unroll
            for (int din = 0; din < D_; ++din)
                acc = fmaf(xp[din], cp[din * 9], acc);
        }
    }
    yact[idx] = qgelu(acc);
}

// ---------------- Stage 6: adapter-up ----------------
__global__ void k_up(const float* __restrict__ yact, const float* __restrict__ uw,
                     const float* __restrict__ ub, float* __restrict__ out)
{
    __shared__ float ys[D_];
    const int pos = blockIdx.x;
    if (threadIdx.x < D_) ys[threadIdx.x] = yact[(size_t)pos * D_ + threadIdx.x];
    __syncthreads();

    for (int c = threadIdx.x; c < C_; c += 256) {
        float acc = ub[c];
        const float* wrow = uw + (size_t)c * D_;
        #pragma unroll
        for (int d = 0; d < D_; ++d) acc = fmaf(ys[d], wrow[d], acc);
        out[(size_t)pos * C_ + c] = acc;
    }
}

extern "C" void kernel_launch(void* const* d_in, const int* in_sizes, int n_in,
                              void* d_out, int out_size, void* d_ws, size_t ws_size,
                              hipStream_t stream) {
    const float* x         = (const float*)d_in[0];
    const float* meta_w1   = (const float*)d_in[1];
    const float* meta_b1   = (const float*)d_in[2];
    const float* meta_w2   = (const float*)d_in[3];
    const float* meta_b2   = (const float*)d_in[4];
    const float* layer_emb = (const float*)d_in[5];
    const float* hyper_w   = (const float*)d_in[6];
    const float* hyper_b   = (const float*)d_in[7];
    const float* down_w    = (const float*)d_in[8];
    const float* down_b    = (const float*)d_in[9];
    const float* up_w      = (const float*)d_in[10];
    const float* up_b      = (const float*)d_in[11];
    float* out = (float*)d_out;

    // workspace layout (floats). pbuf is consumed by k_reduce before k_down
    // runs (stream-serialized), so xact aliases pbuf.
    float* ws     = (float*)d_ws;
    float* pbuf   = ws;                               // NPOS*64
    float* xact   = pbuf;                             // alias, NPOS*64
    float* prompt = ws + (size_t)NPOS * EMB_;         // 2048
    float* conv_w = prompt + B_ * EMB_;               // B*36864
    float* yact   = conv_w + (size_t)B_ * CWROWS;     // NPOS*64

    k_meta<<<NPOS / 4, 256, 0, stream>>>(x, meta_w1, meta_b1, meta_w2, meta_b2, pbuf);
    k_reduce<<<B_, 256, 0, stream>>>(pbuf, prompt);
    k_hyper<<<CWROWS / 256, 256, 0, stream>>>(prompt, layer_emb, hyper_w, hyper_b, conv_w);
    k_down<<<NPOS / 4, 256, 0, stream>>>(x, down_w, down_b, xact);
    k_conv<<<NPOS * D_ / 256, 256, 0, stream>>>(xact, conv_w, yact);
    k_up<<<NPOS, 256, 0, stream>>>(yact, up_w, up_b, out);
}

// Round 2
// 2246.313 us; speedup vs baseline: 1.7180x; 1.7180x over previous
//
#include <hip/hip_runtime.h>
#include <math.h>

#define B_    32
#define H_    28
#define W_    28
#define C_    768
#define D_    64
#define EMB_  64
#define HW_   (H_ * W_)
#define NPOS  (B_ * HW_)          // 25088
#define CWROWS (D_ * D_ * 9)      // 36864

__device__ __forceinline__ float qgelu(float v) {
    return v / (1.f + __expf(-1.702f * v));
}

// ---------------- Stage 1+4 fused: meta MLP + adapter-down ----------------
// Reads x once. pbuf[pos][e] = meta2(relu(meta1(x)));  xact[pos][d] = qgelu(x . down_w[d])
__global__ void k_meta_down(const float* __restrict__ x,
                            const float* __restrict__ w1, const float* __restrict__ b1,
                            const float* __restrict__ w2, const float* __restrict__ b2,
                            const float* __restrict__ dw, const float* __restrict__ db,
                            float* __restrict__ pbuf, float* __restrict__ xact)
{
    __shared__ float xs[4][C_];
    __shared__ float hs[4][EMB_];
    const int wave = threadIdx.x >> 6;
    const int lane = threadIdx.x & 63;
    const int pos  = blockIdx.x * 4 + wave;   // NPOS % 4 == 0

    // stage x row (float4, coalesced)
    {
        const float4* xr4 = (const float4*)(x + (size_t)pos * C_);
        float4* xs4 = (float4*)xs[wave];
        #pragma unroll
        for (int i = 0; i < C_ / 4 / 64; ++i) xs4[lane + i * 64] = xr4[lane + i * 64];
    }
    __syncthreads();

    // two 768-dots per lane: meta1 row `lane`, down row `lane`; 4-way ILP each
    const float4* w1r = (const float4*)(w1 + (size_t)lane * C_);
    const float4* dwr = (const float4*)(dw + (size_t)lane * C_);
    const float4* xs4 = (const float4*)xs[wave];
    float m0 = 0.f, m1 = 0.f, m2 = 0.f, m3 = 0.f;
    float d0 = 0.f, d1 = 0.f, d2 = 0.f, d3 = 0.f;
    #pragma unroll 4
    for (int i = 0; i < C_ / 4; ++i) {
        float4 xv = xs4[i];
        float4 wv = w1r[i];
        float4 dv = dwr[i];
        m0 = fmaf(xv.x, wv.x, m0); m1 = fmaf(xv.y, wv.y, m1);
        m2 = fmaf(xv.z, wv.z, m2); m3 = fmaf(xv.w, wv.w, m3);
        d0 = fmaf(xv.x, dv.x, d0); d1 = fmaf(xv.y, dv.y, d1);
        d2 = fmaf(xv.z, dv.z, d2); d3 = fmaf(xv.w, dv.w, d3);
    }
    hs[wave][lane] = fmaxf((m0 + m1) + (m2 + m3) + b1[lane], 0.f);
    xact[(size_t)pos * D_ + lane] = qgelu((d0 + d1) + (d2 + d3) + db[lane]);
    __syncthreads();

    // meta2: p = hs . w2[lane]
    const float4* w2r = (const float4*)(w2 + (size_t)lane * EMB_);
    const float4* hs4 = (const float4*)hs[wave];
    float p0 = 0.f, p1 = 0.f;
    #pragma unroll
    for (int i = 0; i < EMB_ / 4; i += 2) {
        float4 hv0 = hs4[i],   wv0 = w2r[i];
        float4 hv1 = hs4[i+1], wv1 = w2r[i+1];
        p0 = fmaf(hv0.x, wv0.x, p0); p0 = fmaf(hv0.y, wv0.y, p0);
        p0 = fmaf(hv0.z, wv0.z, p0); p0 = fmaf(hv0.w, wv0.w, p0);
        p1 = fmaf(hv1.x, wv1.x, p1); p1 = fmaf(hv1.y, wv1.y, p1);
        p1 = fmaf(hv1.z, wv1.z, p1); p1 = fmaf(hv1.w, wv1.w, p1);
    }
    pbuf[(size_t)pos * EMB_ + lane] = p0 + p1 + b2[lane];
}

// ---------------- Stage 2: deterministic spatial mean ----------------
__global__ void k_reduce(const float* __restrict__ pbuf, float* __restrict__ prompt)
{
    __shared__ float part[4][EMB_];
    const int b     = blockIdx.x;
    const int lane  = threadIdx.x & 63;
    const int chunk = threadIdx.x >> 6;
    float acc = 0.f;
    for (int i = chunk; i < HW_; i += 4)
        acc += pbuf[((size_t)b * HW_ + i) * EMB_ + lane];
    part[chunk][lane] = acc;
    __syncthreads();
    if (threadIdx.x < EMB_) {
        float s = part[0][threadIdx.x] + part[1][threadIdx.x]
                + part[2][threadIdx.x] + part[3][threadIdx.x];
        prompt[b * EMB_ + threadIdx.x] = s * (1.f / HW_);
    }
}

// ---------------- Stage 3: hypernet -> conv weights, layout [b][tap][din][dout] ----------------
// element f = tap*4096 + din*64 + dout  <->  hyper_w row r = (dout*64+din)*9 + tap
__global__ void k_hyper(const float* __restrict__ prompt, const float* __restrict__ layer_emb,
                        const float* __restrict__ hyper_w, const float* __restrict__ hyper_b,
                        float* __restrict__ cw2)
{
    __shared__ float fused[B_][EMB_];
    const int tid = threadIdx.x;
    for (int i = tid; i < B_ * EMB_; i += 256) {
        int e = i & (EMB_ - 1);
        fused[i >> 6][e] = layer_emb[e] + prompt[i];
    }
    __syncthreads();

    const int f    = blockIdx.x * 256 + tid;   // 0..36863
    const int dout = f & 63;
    const int din  = (f >> 6) & 63;
    const int tap  = f >> 12;
    const int r    = (dout * 64 + din) * 9 + tap;

    float wrow[EMB_];
    const float4* hw4 = (const float4*)(hyper_w + (size_t)r * EMB_);
    #pragma unroll
    for (int i = 0; i < EMB_ / 4; ++i) {
        float4 v = hw4[i];
        wrow[i*4+0] = v.x; wrow[i*4+1] = v.y; wrow[i*4+2] = v.z; wrow[i*4+3] = v.w;
    }
    const float hb = hyper_b[r];

    const int b0 = blockIdx.y * 8;             // 8 samples per block.y
    for (int b = b0; b < b0 + 8; ++b) {
        float a0 = 0.f, a1 = 0.f, a2 = 0.f, a3 = 0.f;
        #pragma unroll
        for (int i = 0; i < EMB_; i += 4) {
            a0 = fmaf(fused[b][i+0], wrow[i+0], a0);
            a1 = fmaf(fused[b][i+1], wrow[i+1], a1);
            a2 = fmaf(fused[b][i+2], wrow[i+2], a2);
            a3 = fmaf(fused[b][i+3], wrow[i+3], a3);
        }
        cw2[(size_t)b * CWROWS + f] = (a0 + a1) + (a2 + a3) + hb;
    }
}

// ---------------- Stage 5: per-sample 3x3 conv + QuickGELU ----------------
// block = (b, h); 4 waves x 7 positions; lane = dout.
// cw2 layout [b][tap][din][dout]; xact [B][H][W][D]; yact [B][H][W][D]
__global__ void k_conv(const float* __restrict__ xact, const float* __restrict__ cw2,
                       float* __restrict__ yact)
{
    __shared__ float xs[W_ * D_];          // one input row   (7168 B)
    __shared__ float ws[3][D_][D_];        // [kw][din][dout] (49152 B)
    const int b    = blockIdx.x / H_;
    const int h    = blockIdx.x % H_;
    const int tid  = threadIdx.x;
    const int wave = tid >> 6;
    const int lane = tid & 63;
    const int wstart = wave * 7;           // 4 waves x 7 = 28 positions

    float acc[7];
    #pragma unroll
    for (int p = 0; p < 7; ++p) acc[p] = 0.f;

    for (int kh = 0; kh < 3; ++kh) {
        const int hh = h + kh - 1;
        const bool valid = (hh >= 0) && (hh < H_);
        __syncthreads();
        if (valid) {
            // stage weights slice for taps kh*3 .. kh*3+2 (3072 float4)
            const float4* src = (const float4*)(cw2 + (size_t)b * CWROWS + (size_t)kh * 3 * D_ * D_);
            float4* dst = (float4*)ws;
            for (int i = tid; i < 3 * D_ * D_ / 4; i += 256) dst[i] = src[i];
            // stage x row hh (448 float4)
            const float4* xsrc = (const float4*)(xact + ((size_t)(b * H_ + hh) * W_) * D_);
            float4* xdst = (float4*)xs;
            for (int i = tid; i < W_ * D_ / 4; i += 256) xdst[i] = xsrc[i];
        }
        __syncthreads();
        if (!valid) continue;

        #pragma unroll 1
        for (int dq = 0; dq < D_ / 4; ++dq) {
            // 9 x-columns cover positions wstart..wstart+6 for kw=0..2
            float4 xv[9];
            #pragma unroll
            for (int i = 0; i < 9; ++i) {
                int col = wstart + i - 1;
                if (col >= 0 && col < W_)
                    xv[i] = *(const float4*)&xs[col * D_ + dq * 4];
                else
                    xv[i] = make_float4(0.f, 0.f, 0.f, 0.f);
            }
            float wr[3][4];
            #pragma unroll
            for (int kw = 0; kw < 3; ++kw)
                #pragma unroll
                for (int j = 0; j < 4; ++j)
                    wr[kw][j] = ws[kw][dq * 4 + j][lane];
            #pragma unroll
            for (int p = 0; p < 7; ++p) {
                #pragma unroll
                for (int kw = 0; kw < 3; ++kw) {
                    const float* xq = (const float*)&xv[p + kw];
                    acc[p] = fmaf(xq[0], wr[kw][0], acc[p]);
                    acc[p] = fmaf(xq[1], wr[kw][1], acc[p]);
                    acc[p] = fmaf(xq[2], wr[kw][2], acc[p]);
                    acc[p] = fmaf(xq[3], wr[kw][3], acc[p]);
                }
            }
        }
    }

    const size_t base = ((size_t)(b * H_ + h) * W_ + wstart) * D_;
    #pragma unroll
    for (int p = 0; p < 7; ++p)
        yact[base + (size_t)p * D_ + lane] = qgelu(acc[p]);
}

// ---------------- Stage 6: adapter-up ----------------
__global__ void k_up(const float* __restrict__ yact, const float* __restrict__ uw,
                     const float* __restrict__ ub, float* __restrict__ out)
{
    __shared__ float ys[D_];
    const int pos = blockIdx.x;
    const int tid = threadIdx.x;
    if (tid < D_) ys[tid] = yact[(size_t)pos * D_ + tid];
    __syncthreads();

    const int c0 = tid, c1 = tid + 256, c2 = tid + 512;
    const float4* r0 = (const float4*)(uw + (size_t)c0 * D_);
    const float4* r1 = (const float4*)(uw + (size_t)c1 * D_);
    const float4* r2 = (const float4*)(uw + (size_t)c2 * D_);
    const float4* ys4 = (const float4*)ys;
    float a0 = 0.f, a1 = 0.f, a2 = 0.f;
    #pragma unroll
    for (int i = 0; i < D_ / 4; ++i) {
        float4 yv = ys4[i];
        float4 w0 = r0[i], w1 = r1[i], w2 = r2[i];
        a0 = fmaf(yv.x, w0.x, a0); a0 = fmaf(yv.y, w0.y, a0);
        a0 = fmaf(yv.z, w0.z, a0); a0 = fmaf(yv.w, w0.w, a0);
        a1 = fmaf(yv.x, w1.x, a1); a1 = fmaf(yv.y, w1.y, a1);
        a1 = fmaf(yv.z, w1.z, a1); a1 = fmaf(yv.w, w1.w, a1);
        a2 = fmaf(yv.x, w2.x, a2); a2 = fmaf(yv.y, w2.y, a2);
        a2 = fmaf(yv.z, w2.z, a2); a2 = fmaf(yv.w, w2.w, a2);
    }
    float* o = out + (size_t)pos * C_;
    o[c0] = a0 + ub[c0];
    o[c1] = a1 + ub[c1];
    o[c2] = a2 + ub[c2];
}

extern "C" void kernel_launch(void* const* d_in, const int* in_sizes, int n_in,
                              void* d_out, int out_size, void* d_ws, size_t ws_size,
                              hipStream_t stream) {
    const float* x         = (const float*)d_in[0];
    const float* meta_w1   = (const float*)d_in[1];
    const float* meta_b1   = (const float*)d_in[2];
    const float* meta_w2   = (const float*)d_in[3];
    const float* meta_b2   = (const float*)d_in[4];
    const float* layer_emb = (const float*)d_in[5];
    const float* hyper_w   = (const float*)d_in[6];
    const float* hyper_b   = (const float*)d_in[7];
    const float* down_w    = (const float*)d_in[8];
    const float* down_b    = (const float*)d_in[9];
    const float* up_w      = (const float*)d_in[10];
    const float* up_b      = (const float*)d_in[11];
    float* out = (float*)d_out;

    // ws layout (floats): pbuf (aliased later by yact) | prompt | conv weights | xact
    float* ws     = (float*)d_ws;
    float* pbuf   = ws;                               // NPOS*64
    float* yact   = pbuf;                             // alias: pbuf dead after k_reduce
    float* prompt = ws + (size_t)NPOS * EMB_;         // 2048
    float* cw2    = prompt + B_ * EMB_;               // B*36864, layout [b][tap][din][dout]
    float* xact   = cw2 + (size_t)B_ * CWROWS;        // NPOS*64

    k_meta_down<<<NPOS / 4, 256, 0, stream>>>(x, meta_w1, meta_b1, meta_w2, meta_b2,
                                              down_w, down_b, pbuf, xact);
    k_reduce<<<B_, 256, 0, stream>>>(pbuf, prompt);
    dim3 hgrid(CWROWS / 256, B_ / 8);
    k_hyper<<<hgrid, 256, 0, stream>>>(prompt, layer_emb, hyper_w, hyper_b, cw2);
    k_conv<<<B_ * H_, 256, 0, stream>>>(xact, cw2, yact);
    k_up<<<NPOS, 256, 0, stream>>>(yact, up_w, up_b, out);
}

// Round 3
// 338.511 us; speedup vs baseline: 11.4006x; 6.6359x over previous
//
#include <hip/hip_runtime.h>
#include <math.h>

#define B_    32
#define H_    28
#define W_    28
#define C_    768
#define D_    64
#define EMB_  64
#define HW_   (H_ * W_)
#define NPOS  (B_ * HW_)          // 25088
#define CWROWS (D_ * D_ * 9)      // 36864

__device__ __forceinline__ float qgelu(float v) {
    return v / (1.f + __expf(-1.702f * v));
}
__device__ __forceinline__ float relu(float v) { return fmaxf(v, 0.f); }

// ---------------- Stage 0: 32x32 tiled transpose ----------------
// dst[c][colOff + r] = src[r][c]; dst row stride dstStride. Block (32,8).
__global__ void k_tr(const float* __restrict__ src, int R, int C,
                     float* __restrict__ dst, int dstStride, int colOff)
{
    __shared__ float tile[32][33];
    const int c0 = blockIdx.x * 32, r0 = blockIdx.y * 32;
    const int tx = threadIdx.x, ty = threadIdx.y;
    #pragma unroll
    for (int i = 0; i < 4; ++i)
        tile[ty + 8 * i][tx] = src[(size_t)(r0 + ty + 8 * i) * C + c0 + tx];
    __syncthreads();
    #pragma unroll
    for (int i = 0; i < 4; ++i)
        dst[(size_t)(c0 + ty + 8 * i) * dstStride + colOff + r0 + tx] = tile[tx][ty + 8 * i];
}

// ---------------- Stage 1+4: tiled GEMM, N=128 (64 relu-h | 64 qgelu-down) ----------------
// x_t chunk-padded k-major: float offset (k,m) = k*192 + (m>>3)*12 + (m&7)
#define XT_OFF(k, m) ((k) * 192 + ((m) >> 3) * 12 + ((m) & 7))

__global__ __launch_bounds__(256, 4)
void k_gemm_md(const float* __restrict__ x, const float* __restrict__ wT,
               const float* __restrict__ b1, const float* __restrict__ db,
               float* __restrict__ hbuf, float* __restrict__ xact)
{
    __shared__ float xt[16 * 192];    // 12 KB
    __shared__ float wt[16][128];     //  8 KB
    const int t  = threadIdx.x;
    const int tm = t & 15, tn = t >> 4;
    const int bm = blockIdx.x;        // 196 blocks, Mt=128

    float acc[8][8];
    #pragma unroll
    for (int i = 0; i < 8; ++i)
        #pragma unroll
        for (int j = 0; j < 8; ++j) acc[i][j] = 0.f;

    for (int k0 = 0; k0 < C_; k0 += 16) {
        __syncthreads();
        // stage x tile [128 rows][16 k] -> transposed chunk-padded LDS
        #pragma unroll
        for (int s = 0; s < 2; ++s) {
            const int j = s * 256 + t;
            const int row = j >> 2, c4 = j & 3;
            float4 v = *(const float4*)(x + (size_t)(bm * 128 + row) * C_ + k0 + c4 * 4);
            xt[XT_OFF(c4 * 4 + 0, row)] = v.x;
            xt[XT_OFF(c4 * 4 + 1, row)] = v.y;
            xt[XT_OFF(c4 * 4 + 2, row)] = v.z;
            xt[XT_OFF(c4 * 4 + 3, row)] = v.w;
        }
        // stage w tile (wT already k-major): contiguous copy
        #pragma unroll
        for (int s = 0; s < 2; ++s) {
            const int j = s * 256 + t;
            const int k = j >> 5, c4 = j & 31;
            *(float4*)&wt[k][c4 * 4] = *(const float4*)(wT + (size_t)(k0 + k) * 128 + c4 * 4);
        }
        __syncthreads();
        #pragma unroll
        for (int k = 0; k < 16; ++k) {
            float a[8], b[8];
            *(float4*)&a[0] = *(const float4*)&xt[XT_OFF(k, tm * 8)];
            *(float4*)&a[4] = *(const float4*)&xt[XT_OFF(k, tm * 8 + 4)];
            *(float4*)&b[0] = *(const float4*)&wt[k][tn * 8];
            *(float4*)&b[4] = *(const float4*)&wt[k][tn * 8 + 4];
            #pragma unroll
            for (int i = 0; i < 8; ++i)
                #pragma unroll
                for (int j = 0; j < 8; ++j)
                    acc[i][j] = fmaf(a[i], b[j], acc[i][j]);
        }
    }

    const int pos0 = bm * 128 + tm * 8;
    if (tn < 8) {                     // meta1 half: relu(acc + b1) -> hbuf
        const int c = tn * 8;
        float4 bb0 = *(const float4*)(b1 + c);
        float4 bb1 = *(const float4*)(b1 + c + 4);
        #pragma unroll
        for (int i = 0; i < 8; ++i) {
            float4 v0 = make_float4(relu(acc[i][0] + bb0.x), relu(acc[i][1] + bb0.y),
                                    relu(acc[i][2] + bb0.z), relu(acc[i][3] + bb0.w));
            float4 v1 = make_float4(relu(acc[i][4] + bb1.x), relu(acc[i][5] + bb1.y),
                                    relu(acc[i][6] + bb1.z), relu(acc[i][7] + bb1.w));
            float* o = hbuf + (size_t)(pos0 + i) * 64 + c;
            *(float4*)o = v0;
            *(float4*)(o + 4) = v1;
        }
    } else {                          // down half: qgelu(acc + db) -> xact
        const int c = (tn - 8) * 8;
        float4 bb0 = *(const float4*)(db + c);
        float4 bb1 = *(const float4*)(db + c + 4);
        #pragma unroll
        for (int i = 0; i < 8; ++i) {
            float4 v0 = make_float4(qgelu(acc[i][0] + bb0.x), qgelu(acc[i][1] + bb0.y),
                                    qgelu(acc[i][2] + bb0.z), qgelu(acc[i][3] + bb0.w));
            float4 v1 = make_float4(qgelu(acc[i][4] + bb1.x), qgelu(acc[i][5] + bb1.y),
                                    qgelu(acc[i][6] + bb1.z), qgelu(acc[i][7] + bb1.w));
            float* o = xact + (size_t)(pos0 + i) * 64 + c;
            *(float4*)o = v0;
            *(float4*)(o + 4) = v1;
        }
    }
}

// ---------------- Stage 2: spatial mean + meta2 (commuted past mean) ----------------
__global__ void k_reduce(const float* __restrict__ hbuf,
                         const float* __restrict__ w2, const float* __restrict__ b2,
                         float* __restrict__ prompt)
{
    __shared__ float part[4][EMB_];
    __shared__ float hm[EMB_];
    const int b     = blockIdx.x;
    const int lane  = threadIdx.x & 63;
    const int chunk = threadIdx.x >> 6;
    float acc = 0.f;
    for (int i = chunk; i < HW_; i += 4)
        acc += hbuf[((size_t)b * HW_ + i) * EMB_ + lane];
    part[chunk][lane] = acc;
    __syncthreads();
    if (threadIdx.x < EMB_) {
        float s = part[0][threadIdx.x] + part[1][threadIdx.x]
                + part[2][threadIdx.x] + part[3][threadIdx.x];
        hm[threadIdx.x] = s * (1.f / HW_);
    }
    __syncthreads();
    if (threadIdx.x < EMB_) {
        const int e = threadIdx.x;
        const float* w2r = w2 + (size_t)e * EMB_;
        float a0 = 0.f, a1 = 0.f, a2 = 0.f, a3 = 0.f;
        #pragma unroll
        for (int i = 0; i < EMB_; i += 4) {
            a0 = fmaf(hm[i + 0], w2r[i + 0], a0);
            a1 = fmaf(hm[i + 1], w2r[i + 1], a1);
            a2 = fmaf(hm[i + 2], w2r[i + 2], a2);
            a3 = fmaf(hm[i + 3], w2r[i + 3], a3);
        }
        prompt[b * EMB_ + e] = (a0 + a1) + (a2 + a3) + b2[e];
    }
}

// ---------------- Stage 3: hypernet -> conv weights [b][tap][din][dout] ----------------
__global__ void k_hyper(const float* __restrict__ prompt, const float* __restrict__ layer_emb,
                        const float* __restrict__ hyper_w, const float* __restrict__ hyper_b,
                        float* __restrict__ cw2)
{
    __shared__ float fused[B_][EMB_];
    const int tid = threadIdx.x;
    for (int i = tid; i < B_ * EMB_; i += 256) {
        int e = i & (EMB_ - 1);
        fused[i >> 6][e] = layer_emb[e] + prompt[i];
    }
    __syncthreads();

    const int f    = blockIdx.x * 256 + tid;   // 0..36863
    const int dout = f & 63;
    const int din  = (f >> 6) & 63;
    const int tap  = f >> 12;
    const int r    = (dout * 64 + din) * 9 + tap;

    float wrow[EMB_];
    const float4* hw4 = (const float4*)(hyper_w + (size_t)r * EMB_);
    #pragma unroll
    for (int i = 0; i < EMB_ / 4; ++i) {
        float4 v = hw4[i];
        wrow[i*4+0] = v.x; wrow[i*4+1] = v.y; wrow[i*4+2] = v.z; wrow[i*4+3] = v.w;
    }
    const float hb = hyper_b[r];

    const int b0 = blockIdx.y * 8;
    for (int b = b0; b < b0 + 8; ++b) {
        float a0 = 0.f, a1 = 0.f, a2 = 0.f, a3 = 0.f;
        #pragma unroll
        for (int i = 0; i < EMB_; i += 4) {
            a0 = fmaf(fused[b][i+0], wrow[i+0], a0);
            a1 = fmaf(fused[b][i+1], wrow[i+1], a1);
            a2 = fmaf(fused[b][i+2], wrow[i+2], a2);
            a3 = fmaf(fused[b][i+3], wrow[i+3], a3);
        }
        cw2[(size_t)b * CWROWS + f] = (a0 + a1) + (a2 + a3) + hb;
    }
}

// ---------------- Stage 5: per-sample 3x3 conv + QuickGELU ----------------
__global__ void k_conv(const float* __restrict__ xact, const float* __restrict__ cw2,
                       float* __restrict__ yact)
{
    __shared__ float xs[W_ * D_];
    __shared__ float ws[3][D_][D_];
    const int b    = blockIdx.x / H_;
    const int h    = blockIdx.x % H_;
    const int tid  = threadIdx.x;
    const int wave = tid >> 6;
    const int lane = tid & 63;
    const int wstart = wave * 7;

    float acc[7];
    #pragma unroll
    for (int p = 0; p < 7; ++p) acc[p] = 0.f;

    for (int kh = 0; kh < 3; ++kh) {
        const int hh = h + kh - 1;
        const bool valid = (hh >= 0) && (hh < H_);
        __syncthreads();
        if (valid) {
            const float4* src = (const float4*)(cw2 + (size_t)b * CWROWS + (size_t)kh * 3 * D_ * D_);
            float4* dst = (float4*)ws;
            for (int i = tid; i < 3 * D_ * D_ / 4; i += 256) dst[i] = src[i];
            const float4* xsrc = (const float4*)(xact + ((size_t)(b * H_ + hh) * W_) * D_);
            float4* xdst = (float4*)xs;
            for (int i = tid; i < W_ * D_ / 4; i += 256) xdst[i] = xsrc[i];
        }
        __syncthreads();
        if (!valid) continue;

        #pragma unroll 1
        for (int dq = 0; dq < D_ / 4; ++dq) {
            float4 xv[9];
            #pragma unroll
            for (int i = 0; i < 9; ++i) {
                int col = wstart + i - 1;
                if (col >= 0 && col < W_)
                    xv[i] = *(const float4*)&xs[col * D_ + dq * 4];
                else
                    xv[i] = make_float4(0.f, 0.f, 0.f, 0.f);
            }
            float wr[3][4];
            #pragma unroll
            for (int kw = 0; kw < 3; ++kw)
                #pragma unroll
                for (int j = 0; j < 4; ++j)
                    wr[kw][j] = ws[kw][dq * 4 + j][lane];
            #pragma unroll
            for (int p = 0; p < 7; ++p) {
                #pragma unroll
                for (int kw = 0; kw < 3; ++kw) {
                    const float* xq = (const float*)&xv[p + kw];
                    acc[p] = fmaf(xq[0], wr[kw][0], acc[p]);
                    acc[p] = fmaf(xq[1], wr[kw][1], acc[p]);
                    acc[p] = fmaf(xq[2], wr[kw][2], acc[p]);
                    acc[p] = fmaf(xq[3], wr[kw][3], acc[p]);
                }
            }
        }
    }

    const size_t base = ((size_t)(b * H_ + h) * W_ + wstart) * D_;
    #pragma unroll
    for (int p = 0; p < 7; ++p)
        yact[base + (size_t)p * D_ + lane] = qgelu(acc[p]);
}

// ---------------- Stage 6: adapter-up, tiled GEMM M=25088 N=768 K=64 ----------------
__global__ void k_up(const float* __restrict__ yact, const float* __restrict__ uw,
                     const float* __restrict__ ub, float* __restrict__ out)
{
    __shared__ float yt[64][67];    // padded: a-reads 2-way max
    __shared__ float wt[128][65];   // padded: b-reads conflict-free broadcasts
    const int t = threadIdx.x, tm = t & 15, tn = t >> 4;
    const int bm = blockIdx.x;      // 392 blocks, Mt=64

    // stage y tile once (scalar stores due to pad)
    #pragma unroll
    for (int s = 0; s < 4; ++s) {
        const int j = s * 256 + t;
        const int row = j >> 4, c4 = j & 15;
        float4 v = *(const float4*)(yact + (size_t)(bm * 64 + row) * 64 + c4 * 4);
        yt[row][c4 * 4 + 0] = v.x; yt[row][c4 * 4 + 1] = v.y;
        yt[row][c4 * 4 + 2] = v.z; yt[row][c4 * 4 + 3] = v.w;
    }

    for (int nc = 0; nc < 6; ++nc) {
        __syncthreads();
        // stage weight chunk: 128 rows (n) x 64 (k), direct copy of up_w rows
        #pragma unroll
        for (int s = 0; s < 8; ++s) {
            const int j = s * 256 + t;
            const int row = j >> 4, c4 = j & 15;
            float4 v = *(const float4*)(uw + (size_t)(nc * 128 + row) * 64 + c4 * 4);
            wt[row][c4 * 4 + 0] = v.x; wt[row][c4 * 4 + 1] = v.y;
            wt[row][c4 * 4 + 2] = v.z; wt[row][c4 * 4 + 3] = v.w;
        }
        __syncthreads();

        float acc[4][8];
        #pragma unroll
        for (int i = 0; i < 4; ++i)
            #pragma unroll
            for (int j = 0; j < 8; ++j) acc[i][j] = 0.f;

        for (int k = 0; k < D_; ++k) {
            float a[4], b[8];
            #pragma unroll
            for (int i = 0; i < 4; ++i) a[i] = yt[tm * 4 + i][k];
            #pragma unroll
            for (int j = 0; j < 8; ++j) b[j] = wt[tn * 8 + j][k];
            #pragma unroll
            for (int i = 0; i < 4; ++i)
                #pragma unroll
                for (int j = 0; j < 8; ++j)
                    acc[i][j] = fmaf(a[i], b[j], acc[i][j]);
        }

        const int c = nc * 128 + tn * 8;
        float4 u0 = *(const float4*)(ub + c);
        float4 u1 = *(const float4*)(ub + c + 4);
        #pragma unroll
        for (int i = 0; i < 4; ++i) {
            const int pos = bm * 64 + tm * 4 + i;
            float* o = out + (size_t)pos * C_ + c;
            *(float4*)o = make_float4(acc[i][0] + u0.x, acc[i][1] + u0.y,
                                      acc[i][2] + u0.z, acc[i][3] + u0.w);
            *(float4*)(o + 4) = make_float4(acc[i][4] + u1.x, acc[i][5] + u1.y,
                                            acc[i][6] + u1.z, acc[i][7] + u1.w);
        }
    }
}

extern "C" void kernel_launch(void* const* d_in, const int* in_sizes, int n_in,
                              void* d_out, int out_size, void* d_ws, size_t ws_size,
                              hipStream_t stream) {
    const float* x         = (const float*)d_in[0];
    const float* meta_w1   = (const float*)d_in[1];
    const float* meta_b1   = (const float*)d_in[2];
    const float* meta_w2   = (const float*)d_in[3];
    const float* meta_b2   = (const float*)d_in[4];
    const float* layer_emb = (const float*)d_in[5];
    const float* hyper_w   = (const float*)d_in[6];
    const float* hyper_b   = (const float*)d_in[7];
    const float* down_w    = (const float*)d_in[8];
    const float* down_b    = (const float*)d_in[9];
    const float* up_w      = (const float*)d_in[10];
    const float* up_b      = (const float*)d_in[11];
    float* out = (float*)d_out;

    // ws layout (floats). wT and cw2 share a region: wT is dead before k_hyper
    // writes cw2. yact aliases hbuf (hbuf dead after k_reduce).
    float* ws     = (float*)d_ws;
    float* hbuf   = ws;                               // NPOS*64
    float* yact   = hbuf;                             // alias
    float* xact   = ws + (size_t)NPOS * 64;           // NPOS*64
    float* prompt = xact + (size_t)NPOS * 64;         // 2048
    float* wT     = prompt + B_ * EMB_;               // 768*128 (then clobbered by cw2)
    float* cw2    = wT;                               // B*36864

    // transpose w1 -> wT cols 0..63, down_w -> wT cols 64..127
    dim3 trb(32, 8);
    k_tr<<<dim3(C_ / 32, EMB_ / 32), trb, 0, stream>>>(meta_w1, EMB_, C_, wT, 128, 0);
    k_tr<<<dim3(C_ / 32, D_ / 32),   trb, 0, stream>>>(down_w,  D_,   C_, wT, 128, 64);

    k_gemm_md<<<NPOS / 128, 256, 0, stream>>>(x, wT, meta_b1, down_b, hbuf, xact);
    k_reduce<<<B_, 256, 0, stream>>>(hbuf, meta_w2, meta_b2, prompt);
    dim3 hgrid(CWROWS / 256, B_ / 8);
    k_hyper<<<hgrid, 256, 0, stream>>>(prompt, layer_emb, hyper_w, hyper_b, cw2);
    k_conv<<<B_ * H_, 256, 0, stream>>>(xact, cw2, yact);
    k_up<<<NPOS / 64, 256, 0, stream>>>(yact, up_w, up_b, out);
}